// Round 1
// baseline (284.216 us; speedup 1.0000x reference)
//
#include <hip/hip_runtime.h>
#include <hip/hip_bf16.h>
#include <math.h>

typedef __attribute__((ext_vector_type(8))) __bf16 bf16x8;
typedef __attribute__((ext_vector_type(4))) __bf16 bf16x4;
typedef __attribute__((ext_vector_type(4))) float f32x4;
typedef __attribute__((ext_vector_type(4))) short short4_t;

#define D_MODEL 1024
#define SEQ     2048
#define BATCH   4
#define NH      16
#define HD      64
#define MROWS   (BATCH * SEQ)   // 8192

// 0.125 (1/sqrt(64)) * log2(e): folded into Q at the QKV-GEMM epilogue
#define SCALE_LOG2E 0.18033688011112042f

__device__ __forceinline__ void gld_lds16(const __bf16* g, __bf16* l) {
  __builtin_amdgcn_global_load_lds(
      (const __attribute__((address_space(1))) void*)g,
      (__attribute__((address_space(3))) void*)l, 16, 0, 0);
}

// ---------------- convert x: fp32 -> bf16, vectorized ----------------
__global__ __launch_bounds__(256) void cvt_x(const float* __restrict__ in,
                                             __bf16* __restrict__ out) {
  int i = (blockIdx.x * 256 + threadIdx.x) * 4;
  float4 f = *(const float4*)(in + i);
  bf16x4 o;
  o.x = (__bf16)f.x; o.y = (__bf16)f.y; o.z = (__bf16)f.z; o.w = (__bf16)f.w;
  *(bf16x4*)(out + i) = o;
}

// ------- convert + transpose weight: fp32 [K][N] -> bf16 [N][K] -------
__global__ __launch_bounds__(256) void cvt_wt(const float* __restrict__ W,
                                              __bf16* __restrict__ Wt) {
  __shared__ __bf16 t[32][33];
  int tx = threadIdx.x, ty = threadIdx.y;   // block (32,8)
  int n0 = blockIdx.x * 32, k0 = blockIdx.y * 32;
#pragma unroll
  for (int j = 0; j < 32; j += 8)
    t[ty + j][tx] = (__bf16)W[(size_t)(k0 + ty + j) * D_MODEL + n0 + tx];
  __syncthreads();
#pragma unroll
  for (int j = 0; j < 32; j += 8)
    Wt[(size_t)(n0 + ty + j) * D_MODEL + k0 + tx] = t[tx][ty + j];
}

// ---------------- GEMM: C[M,N] = A[M,K] @ Bt[N,K]^T  (bf16)
// T3 minimum 2-phase: LDS double-buffered; each K-step issues the NEXT
// tile's global_load_lds BEFORE the ds_read+MFMA of the current tile, then a
// single __syncthreads() (implicit vmcnt(0)+lgkmcnt(0) drain) publishes it.
// Stage targets buf cur^1 while reads hit buf cur -> race-free with ONE
// barrier per K-step; HBM latency of the prefetch hides under 16 MFMAs.
// Operand-swap trick: passing (Bfrag, Afrag) to MFMA yields C^T tiles, so a
// lane holds 4 CONSECUTIVE minor-dim outputs -> vector stores (b64/b128)
// instead of 4 scalar stores. Orientation chosen per output layout:
// EPI 0 (SWAP): QK, N=2048. lane: token=l16, d=quad*4+i -> bf16x4 to [b,h,n,d]
//               (which = Q or K per 1024-col block; Q pre-scaled)
// EPI 1 (no swap): V, N=1024. lane: d=l16, token=quad*4+i -> bf16x4 to [b,h,d,n]
// EPI 2 (SWAP): proj, N=1024 fp32. lane: row=l16, col=quad*4+i -> float4+bias
template <int EPI>
__global__ __launch_bounds__(256) void gemm_bt(const __bf16* __restrict__ A,
                                               const __bf16* __restrict__ Bt,
                                               const float* __restrict__ bias,
                                               void* __restrict__ Cout) {
  constexpr int Kd = 1024;
  constexpr bool SWAP = (EPI != 1);
  __shared__ __bf16 As[2][128 * 32];
  __shared__ __bf16 Bs[2][128 * 32];
  const int tid = threadIdx.x;
  const int lane = tid & 63;
  const int w = tid >> 6;
  const int quad = lane >> 4, l16 = lane & 15;
  const int wr = w >> 1, wc = w & 1;
  const int tm = blockIdx.y * 128, tn = blockIdx.x * 128;

  f32x4 acc[4][4] = {};

  const int u0 = (w * 2) * 64 + lane;
  const int u1 = u0 + 64;
  const int rA0 = u0 >> 2, kofs0 = (u0 & 3) * 8;
  const int rA1 = u1 >> 2, kofs1 = (u1 & 3) * 8;
  const __bf16* gA0 = A + (size_t)(tm + rA0) * Kd + kofs0;
  const __bf16* gA1 = A + (size_t)(tm + rA1) * Kd + kofs1;
  const __bf16* gB0 = Bt + (size_t)(tn + rA0) * Kd + kofs0;
  const __bf16* gB1 = Bt + (size_t)(tn + rA1) * Kd + kofs1;
  const int ldst0 = (w * 2 + 0) * 512;
  const int ldst1 = (w * 2 + 1) * 512;

  auto stageg = [&](int k0s, int buf) {
    gld_lds16(gA0 + k0s, &As[buf][ldst0]);
    gld_lds16(gA1 + k0s, &As[buf][ldst1]);
    gld_lds16(gB0 + k0s, &Bs[buf][ldst0]);
    gld_lds16(gB1 + k0s, &Bs[buf][ldst1]);
  };

  // prologue: stage tile 0, publish
  stageg(0, 0);
  __syncthreads();

  int cur = 0;
#pragma unroll 2
  for (int k0 = 0; k0 < Kd; k0 += 32) {
    // issue NEXT tile's loads first (fire-and-forget into the other buffer)
    if (k0 + 32 < Kd) stageg(k0 + 32, cur ^ 1);

    bf16x8 af[4], bfr[4];
#pragma unroll
    for (int t = 0; t < 4; ++t) {
      af[t]  = *(const bf16x8*)&As[cur][(wr * 64 + t * 16 + l16) * 32 + quad * 8];
      bfr[t] = *(const bf16x8*)&Bs[cur][(wc * 64 + t * 16 + l16) * 32 + quad * 8];
    }
#pragma unroll
    for (int mt = 0; mt < 4; ++mt)
#pragma unroll
      for (int nt = 0; nt < 4; ++nt) {
        if constexpr (SWAP)
          acc[mt][nt] = __builtin_amdgcn_mfma_f32_16x16x32_bf16(
              bfr[nt], af[mt], acc[mt][nt], 0, 0, 0);
        else
          acc[mt][nt] = __builtin_amdgcn_mfma_f32_16x16x32_bf16(
              af[mt], bfr[nt], acc[mt][nt], 0, 0, 0);
      }
    // one barrier per K-step: drains this iteration's prefetch (vmcnt(0))
    // and fences all waves' reads of buf cur before it is overwritten.
    __syncthreads();
    cur ^= 1;
  }

#pragma unroll
  for (int mt = 0; mt < 4; ++mt)
#pragma unroll
    for (int nt = 0; nt < 4; ++nt) {
      if constexpr (EPI == 2) {
        // C^T tile: row of D = out col, col of D = out row (token)
        int gm  = tm + wr * 64 + mt * 16 + l16;        // token
        int gn0 = tn + wc * 64 + nt * 16 + quad * 4;   // col base
        float4 bv = *(const float4*)&bias[gn0];
        float4 o;
        o.x = acc[mt][nt][0] + bv.x;
        o.y = acc[mt][nt][1] + bv.y;
        o.z = acc[mt][nt][2] + bv.z;
        o.w = acc[mt][nt][3] + bv.w;
        *(float4*)&((float*)Cout)[(size_t)gm * 1024 + gn0] = o;
      } else if constexpr (EPI == 0) {
        int gm = tm + wr * 64 + mt * 16 + l16;         // token
        int f0 = tn + wc * 64 + nt * 16 + quad * 4;    // 0..2047 (Q|K)
        int which = f0 >> 10, col = f0 & 1023;
        int b = gm >> 11, nn = gm & 2047, h = col >> 6, d = col & 63;
        float s = (which == 0) ? SCALE_LOG2E : 1.0f;
        bf16x4 o;
        o[0] = (__bf16)(acc[mt][nt][0] * s);
        o[1] = (__bf16)(acc[mt][nt][1] * s);
        o[2] = (__bf16)(acc[mt][nt][2] * s);
        o[3] = (__bf16)(acc[mt][nt][3] * s);
        __bf16* op = (__bf16*)Cout + (size_t)which * (BATCH * SEQ * (size_t)D_MODEL) +
                     ((size_t)(b * NH + h) * SEQ + nn) * HD + d;
        *(bf16x4*)op = o;
      } else {   // EPI 1: V transposed, natural orientation
        int gm0 = tm + wr * 64 + mt * 16 + quad * 4;   // token base
        int gn  = tn + wc * 64 + nt * 16 + l16;        // feature 0..1023
        int b = gm0 >> 11, nn0 = gm0 & 2047, h = gn >> 6, d = gn & 63;
        bf16x4 o;
        o[0] = (__bf16)acc[mt][nt][0];
        o[1] = (__bf16)acc[mt][nt][1];
        o[2] = (__bf16)acc[mt][nt][2];
        o[3] = (__bf16)acc[mt][nt][3];
        __bf16* op = (__bf16*)Cout + ((size_t)(b * NH + h) * HD + d) * SEQ + nn0;
        *(bf16x4*)op = o;
      }
    }
}

// ---------------- causal flash attention, register-PV, double-buffered ----
// grid (8, 64), block 256 (4 waves). Block pr handles q-tile pair
// (pr, 15-pr), 128 rows each; wave w owns rows tile*128+w*32 .. +32.
// S^T = mfma_16x16x32(Kfrag, Qfrag): lane holds S[q=l16][k=quad*4+i] -- this
// is EXACTLY the A-operand layout of mfma_f32_16x16x16_bf16 (k=quad*4+j), so
// PV runs straight from registers: no P LDS round-trip at all.
// K LDS is XOR-swizzled (16B slot s of key r holds global slot s^((r>>1)&3)):
// rule-21 pattern -- global_load_lds dest stays LINEAR, the global SOURCE is
// pre-swizzled, and the ds_read_b128 applies the same involution. This makes
// each 8-lane service group cover all 32 banks (was 4-way on banks 0-3 for
// even l16). V staged with XOR swizzle (unit = d*8 + ((k>>3)^(d&7))) so the
// b64 B-frag reads sit at the b64 floor. K/V double-buffered: 1 barrier/iter,
// prefetch of iter+1 overlaps compute of iter.
__global__ __launch_bounds__(256, 2) void attn(const __bf16* __restrict__ Q,
                                               const __bf16* __restrict__ K,
                                               const __bf16* __restrict__ Vt,
                                               __bf16* __restrict__ ctx) {
  const int tid = threadIdx.x;
  const int lane = tid & 63, w = tid >> 6;
  const int quad = lane >> 4, l16 = lane & 15;
  const int pr = blockIdx.x;            // 0..7
  const int bh = blockIdx.y;
  const int tile0 = pr, tile1 = 15 - pr;
  const __bf16* qb = Q + (size_t)bh * SEQ * HD;
  const __bf16* kb = K + (size_t)bh * SEQ * HD;
  const __bf16* vb = Vt + (size_t)bh * HD * SEQ;

  __shared__ __bf16 KsAll[2 * 4096];   // [buf][half*2048 + key*32 + slotswz*8]
  __shared__ __bf16 VsAll[2 * 4096];   // [buf][d*64 + ((k>>3)^(d&7))*8 + (k&7)]

  const int qmin[2] = {tile0 * 128 + w * 32, tile1 * 128 + w * 32};

  // Q fragments (B-operand, scale pre-folded), both phases
  bf16x8 aq[2][2][2];
#pragma unroll
  for (int p = 0; p < 2; ++p)
#pragma unroll
    for (int qq = 0; qq < 2; ++qq)
#pragma unroll
      for (int kk = 0; kk < 2; ++kk)
        aq[p][qq][kk] = *(const bf16x8*)(qb + (size_t)(qmin[p] + qq * 16 + l16) * HD +
                                         kk * 32 + quad * 8);

  f32x4 acc[2][2][4] = {};   // [phase][qq][cd] rows q=quad*4+i, cols d=cd*16+l16
  float lsum[2][2] = {};     // [phase][qq] per-lane partial for q-col = l16

  // staging decode. K (swizzled): unit u -> key r=(u>>2)&63, half h=u>>8,
  // elem-group e=(u&3)^((u>>3)&3)  [= (u&3)^((r>>1)&3), the slot involution].
  // V (swizzled): unit u -> d=u>>3, kc=(u&7)^(d&7).
  const int u0 = w * 128 + lane;
  const int u1 = u0 + 64;
  const int kOffG0 = ((u0 >> 2) & 63) * HD + (u0 >> 8) * 32 +
                     (((u0 & 3) ^ ((u0 >> 3) & 3)) * 8);
  const int kOffG1 = ((u1 >> 2) & 63) * HD + (u1 >> 8) * 32 +
                     (((u1 & 3) ^ ((u1 >> 3) & 3)) * 8);
  const int vd0 = u0 >> 3, vd1 = u1 >> 3;
  const int vOffG0 = vd0 * SEQ + (((u0 & 7) ^ (vd0 & 7)) * 8);
  const int vOffG1 = vd1 * SEQ + (((u1 & 7) ^ (vd1 & 7)) * 8);
  // K-read slot swizzle (loop-invariant): slot = quad ^ ((l16>>1)&3)
  const int ksw = (quad ^ ((l16 >> 1) & 3)) * 8;

  auto stage = [&](int k0s, int bufsel) {
    __bf16* Kb = KsAll + bufsel * 4096;
    __bf16* Vb = VsAll + bufsel * 4096;
    gld_lds16(kb + (size_t)k0s * HD + kOffG0, Kb + u0 * 8);
    gld_lds16(kb + (size_t)k0s * HD + kOffG1, Kb + u1 * 8);
    gld_lds16(vb + k0s + vOffG0, Vb + u0 * 8);
    gld_lds16(vb + k0s + vOffG1, Vb + u1 * 8);
  };

  const int nIter = 2 * tile1 + 2;
  stage(0, 0);

  for (int it = 0; it < nIter; ++it) {
    __syncthreads();   // buf[it&1] staged; all waves done with buf[(it+1)&1]
    if (it + 1 < nIter) stage((it + 1) * 64, (it + 1) & 1);

    const int k0 = it * 64;
    if (k0 <= qmin[1] + 31) {   // phase-1 active (superset of phase-0 range)
      const __bf16* Kb = KsAll + (it & 1) * 4096;
      const __bf16* Vb = VsAll + (it & 1) * 4096;

      bf16x8 bk[4][2];          // A-operand K frags: rows = keys
#pragma unroll
      for (int kt = 0; kt < 4; ++kt)
#pragma unroll
        for (int kk = 0; kk < 2; ++kk)
          bk[kt][kk] = *(const bf16x8*)&Kb[kk * 2048 + (kt * 16 + l16) * 32 + ksw];

      // V B-frags for K=16 PV: vf[kt][cd] = V[k=kt*16+quad*4 ..+3][d=cd*16+l16]
      short4_t vf[4][4];
#pragma unroll
      for (int kt = 0; kt < 4; ++kt)
#pragma unroll
        for (int cd = 0; cd < 4; ++cd)
          vf[kt][cd] = *(const short4_t*)&Vb[(cd * 16 + l16) * 64 +
                                             (((kt * 2 + (quad >> 1)) ^ (l16 & 7)) * 8) +
                                             (quad & 1) * 4];

#pragma unroll
      for (int p = 0; p < 2; ++p) {
        if (k0 > qmin[p] + 31) continue;
        // S^T[k][q]: rows k = k0+kt*16+quad*4+i, cols q = qmin[p]+qq*16+l16
        f32x4 St[4][2] = {};
#pragma unroll
        for (int kt = 0; kt < 4; ++kt)
#pragma unroll
          for (int qq = 0; qq < 2; ++qq) {
            St[kt][qq] = __builtin_amdgcn_mfma_f32_16x16x32_bf16(
                bk[kt][0], aq[p][qq][0], St[kt][qq], 0, 0, 0);
            St[kt][qq] = __builtin_amdgcn_mfma_f32_16x16x32_bf16(
                bk[kt][1], aq[p][qq][1], St[kt][qq], 0, 0, 0);
          }
        const bool full = (k0 + 63 <= qmin[p]);
#pragma unroll
        for (int kt = 0; kt < 4; ++kt)
#pragma unroll
          for (int qq = 0; qq < 2; ++qq) {
            float e0 = __builtin_amdgcn_exp2f(St[kt][qq][0]);
            float e1 = __builtin_amdgcn_exp2f(St[kt][qq][1]);
            float e2 = __builtin_amdgcn_exp2f(St[kt][qq][2]);
            float e3 = __builtin_amdgcn_exp2f(St[kt][qq][3]);
            if (!full) {
              int kg = k0 + kt * 16 + quad * 4;
              int qg = qmin[p] + qq * 16 + l16;
              if (kg + 0 > qg) e0 = 0.f;
              if (kg + 1 > qg) e1 = 0.f;
              if (kg + 2 > qg) e2 = 0.f;
              if (kg + 3 > qg) e3 = 0.f;
            }
            lsum[p][qq] += (e0 + e1) + (e2 + e3);
            short4_t ap;
            ap[0] = __builtin_bit_cast(short, (__bf16)e0);
            ap[1] = __builtin_bit_cast(short, (__bf16)e1);
            ap[2] = __builtin_bit_cast(short, (__bf16)e2);
            ap[3] = __builtin_bit_cast(short, (__bf16)e3);
            // PV straight from registers: O[q][d] tiles over d
#pragma unroll
            for (int cd = 0; cd < 4; ++cd)
              acc[p][qq][cd] = __builtin_amdgcn_mfma_f32_16x16x16bf16_1k(
                  ap, vf[kt][cd], acc[p][qq][cd], 0, 0, 0);
          }
      }
    }
  }

  const int bb = bh >> 4, hh = bh & 15;
#pragma unroll
  for (int p = 0; p < 2; ++p) {
#pragma unroll
    for (int qq = 0; qq < 2; ++qq) {
      float s = lsum[p][qq];
      s += __shfl_xor(s, 16);
      s += __shfl_xor(s, 32);   // all lanes: total for q-col = own l16
      float rinv[4];
#pragma unroll
      for (int i = 0; i < 4; ++i)
        rinv[i] = 1.0f / __shfl(s, (lane & 48) + quad * 4 + i);
#pragma unroll
      for (int c = 0; c < 4; ++c)
#pragma unroll
        for (int i = 0; i < 4; ++i) {
          int q = qmin[p] + qq * 16 + quad * 4 + i;
          float o = acc[p][qq][c][i] * rinv[i];
          ctx[((size_t)(bb * SEQ + q)) * D_MODEL + hh * HD + c * 16 + l16] = (__bf16)o;
        }
    }
  }
}

extern "C" void kernel_launch(void* const* d_in, const int* in_sizes, int n_in,
                              void* d_out, int out_size, void* d_ws, size_t ws_size,
                              hipStream_t stream) {
  const float* x  = (const float*)d_in[0];
  const float* Wq = (const float*)d_in[1];
  const float* Wk = (const float*)d_in[2];
  const float* Wv = (const float*)d_in[3];
  const float* Wo = (const float*)d_in[4];
  const float* bo = (const float*)d_in[5];
  float* out = (float*)d_out;
  char* ws = (char*)d_ws;
  const size_t MB = 1024 * 1024;
  __bf16* xb   = (__bf16*)(ws);             // 16 MB; reused as ctx after attn
  __bf16* Wqkv = (__bf16*)(ws + 16 * MB);   // 6 MB: Wqt|Wkt|Wvt contiguous
  __bf16* Wot  = (__bf16*)(ws + 22 * MB);   // 2 MB
  __bf16* Qh   = (__bf16*)(ws + 24 * MB);   // 16 MB [b,h,n,d], pre-scaled
  __bf16* Kh   = (__bf16*)(ws + 40 * MB);   // 16 MB [b,h,n,d]
  __bf16* Vth  = (__bf16*)(ws + 56 * MB);   // 16 MB [b,h,d,n]
  __bf16* ctx  = xb;                        // alias: xb dead after QKV GEMM

  cvt_x<<<MROWS * D_MODEL / (256 * 4), 256, 0, stream>>>(x, xb);
  dim3 tb(32, 8);
  cvt_wt<<<dim3(32, 32), tb, 0, stream>>>(Wq, Wqkv);
  cvt_wt<<<dim3(32, 32), tb, 0, stream>>>(Wk, Wqkv + 1024 * 1024);
  cvt_wt<<<dim3(32, 32), tb, 0, stream>>>(Wv, Wqkv + 2 * 1024 * 1024);
  cvt_wt<<<dim3(32, 32), tb, 0, stream>>>(Wo, Wot);

  // QK projection (swapped-operand epilogue), then V projection (natural)
  gemm_bt<0><<<dim3(16, 64), 256, 0, stream>>>(xb, Wqkv, nullptr, Qh);
  gemm_bt<1><<<dim3(8, 64), 256, 0, stream>>>(xb, Wqkv + 2 * 1024 * 1024, nullptr, Vth);

  attn<<<dim3(8, BATCH * NH), 256, 0, stream>>>(Qh, Kh, Vth, ctx);

  gemm_bt<2><<<dim3(8, 64), 256, 0, stream>>>(ctx, Wot, bo, out);
}

// Round 2
// 283.618 us; speedup vs baseline: 1.0021x; 1.0021x over previous
//
#include <hip/hip_runtime.h>
#include <hip/hip_bf16.h>
#include <math.h>

typedef __attribute__((ext_vector_type(8))) __bf16 bf16x8;
typedef __attribute__((ext_vector_type(4))) __bf16 bf16x4;
typedef __attribute__((ext_vector_type(4))) float f32x4;
typedef __attribute__((ext_vector_type(4))) short short4_t;

#define D_MODEL 1024
#define SEQ     2048
#define BATCH   4
#define NH      16
#define HD      64
#define MROWS   (BATCH * SEQ)   // 8192

// 0.125 (1/sqrt(64)) * log2(e): folded into Q at the QKV-GEMM epilogue
#define SCALE_LOG2E 0.18033688011112042f

__device__ __forceinline__ void gld_lds16(const __bf16* g, __bf16* l) {
  __builtin_amdgcn_global_load_lds(
      (const __attribute__((address_space(1))) void*)g,
      (__attribute__((address_space(3))) void*)l, 16, 0, 0);
}

// ---------------- convert x: fp32 -> bf16, vectorized ----------------
__global__ __launch_bounds__(256) void cvt_x(const float* __restrict__ in,
                                             __bf16* __restrict__ out) {
  int i = (blockIdx.x * 256 + threadIdx.x) * 4;
  float4 f = *(const float4*)(in + i);
  bf16x4 o;
  o.x = (__bf16)f.x; o.y = (__bf16)f.y; o.z = (__bf16)f.z; o.w = (__bf16)f.w;
  *(bf16x4*)(out + i) = o;
}

// ------- convert + transpose weight: fp32 [K][N] -> bf16 [N][K] -------
__global__ __launch_bounds__(256) void cvt_wt(const float* __restrict__ W,
                                              __bf16* __restrict__ Wt) {
  __shared__ __bf16 t[32][33];
  int tx = threadIdx.x, ty = threadIdx.y;   // block (32,8)
  int n0 = blockIdx.x * 32, k0 = blockIdx.y * 32;
#pragma unroll
  for (int j = 0; j < 32; j += 8)
    t[ty + j][tx] = (__bf16)W[(size_t)(k0 + ty + j) * D_MODEL + n0 + tx];
  __syncthreads();
#pragma unroll
  for (int j = 0; j < 32; j += 8)
    Wt[(size_t)(n0 + ty + j) * D_MODEL + k0 + tx] = t[tx][ty + j];
}

// ---------------- GEMM: C[M,N] = A[M,K] @ Bt[N,K]^T  (bf16)
// T4 counted-vmcnt pipeline, depth 2: tile t lives in LDS buffer t%3.
// Per K-step:  s_waitcnt vmcnt(4)  (own 4 loads of tile i landed; the 8
// loads of tiles i+1,i+2 stay IN FLIGHT across the barrier -- never drain
// to 0 in the loop)  ->  raw s_barrier (no compiler vmcnt(0) drain)  ->
// stage tile i+2 (overwrites tile i-1's buffer; safe: all reads of i-1
// finished before the barrier we just passed)  ->  ds_read + 16 MFMA.
// Last two iterations peeled (vmcnt(4) then vmcnt(0)).
// Operand-swap trick: passing (Bfrag, Afrag) to MFMA yields C^T tiles, so a
// lane holds 4 CONSECUTIVE minor-dim outputs -> vector stores (b64/b128)
// instead of 4 scalar stores. Orientation chosen per output layout:
// EPI 0 (SWAP): QK, N=2048. lane: token=l16, d=quad*4+i -> bf16x4 to [b,h,n,d]
//               (which = Q or K per 1024-col block; Q pre-scaled)
// EPI 1 (no swap): V, N=1024. lane: d=l16, token=quad*4+i -> bf16x4 to [b,h,d,n]
// EPI 2 (SWAP): proj, N=1024 fp32. lane: row=l16, col=quad*4+i -> float4+bias
template <int EPI>
__global__ __launch_bounds__(256) void gemm_bt(const __bf16* __restrict__ A,
                                               const __bf16* __restrict__ Bt,
                                               const float* __restrict__ bias,
                                               void* __restrict__ Cout) {
  constexpr int Kd = 1024;
  constexpr int NT = Kd / 32;          // 32 K-tiles
  constexpr bool SWAP = (EPI != 1);
  __shared__ __bf16 As[3 * 4096];      // 3 buffers x 128x32
  __shared__ __bf16 Bs[3 * 4096];
  const int tid = threadIdx.x;
  const int lane = tid & 63;
  const int w = tid >> 6;
  const int quad = lane >> 4, l16 = lane & 15;
  const int wr = w >> 1, wc = w & 1;
  const int tm = blockIdx.y * 128, tn = blockIdx.x * 128;

  f32x4 acc[4][4] = {};

  const int u0 = (w * 2) * 64 + lane;
  const int u1 = u0 + 64;
  const int rA0 = u0 >> 2, kofs0 = (u0 & 3) * 8;
  const int rA1 = u1 >> 2, kofs1 = (u1 & 3) * 8;
  const __bf16* gA0 = A + (size_t)(tm + rA0) * Kd + kofs0;
  const __bf16* gA1 = A + (size_t)(tm + rA1) * Kd + kofs1;
  const __bf16* gB0 = Bt + (size_t)(tn + rA0) * Kd + kofs0;
  const __bf16* gB1 = Bt + (size_t)(tn + rA1) * Kd + kofs1;
  const int ldst0 = (w * 2 + 0) * 512;
  const int ldst1 = (w * 2 + 1) * 512;

  auto stageg = [&](int k0s, int bi) {
    gld_lds16(gA0 + k0s, As + bi * 4096 + ldst0);
    gld_lds16(gA1 + k0s, As + bi * 4096 + ldst1);
    gld_lds16(gB0 + k0s, Bs + bi * 4096 + ldst0);
    gld_lds16(gB1 + k0s, Bs + bi * 4096 + ldst1);
  };

  auto compute = [&](int bi) {
    const __bf16* Ab = As + bi * 4096;
    const __bf16* Bb = Bs + bi * 4096;
    bf16x8 af[4], bfr[4];
#pragma unroll
    for (int t = 0; t < 4; ++t) {
      af[t]  = *(const bf16x8*)&Ab[(wr * 64 + t * 16 + l16) * 32 + quad * 8];
      bfr[t] = *(const bf16x8*)&Bb[(wc * 64 + t * 16 + l16) * 32 + quad * 8];
    }
#pragma unroll
    for (int mt = 0; mt < 4; ++mt)
#pragma unroll
      for (int nt = 0; nt < 4; ++nt) {
        if constexpr (SWAP)
          acc[mt][nt] = __builtin_amdgcn_mfma_f32_16x16x32_bf16(
              bfr[nt], af[mt], acc[mt][nt], 0, 0, 0);
        else
          acc[mt][nt] = __builtin_amdgcn_mfma_f32_16x16x32_bf16(
              af[mt], bfr[nt], acc[mt][nt], 0, 0, 0);
      }
  };

  // prologue: 2 tiles in flight (8 gld_lds outstanding)
  stageg(0, 0);
  stageg(32, 1);

  int bi = 0, bs = 2;
#pragma unroll 3
  for (int i = 0; i < NT - 2; ++i) {
    asm volatile("s_waitcnt vmcnt(4)" ::: "memory");
    __builtin_amdgcn_s_barrier();
    __builtin_amdgcn_sched_barrier(0);
    stageg((i + 2) * 32, bs);
    compute(bi);
    bi = (bi == 2) ? 0 : bi + 1;
    bs = (bs == 2) ? 0 : bs + 1;
  }
  // peeled iter NT-2: tiles NT-2, NT-1 in flight
  asm volatile("s_waitcnt vmcnt(4)" ::: "memory");
  __builtin_amdgcn_s_barrier();
  __builtin_amdgcn_sched_barrier(0);
  compute(bi);
  bi = (bi == 2) ? 0 : bi + 1;
  // peeled iter NT-1: last tile -- only here do we drain fully
  asm volatile("s_waitcnt vmcnt(0)" ::: "memory");
  __builtin_amdgcn_s_barrier();
  __builtin_amdgcn_sched_barrier(0);
  compute(bi);

#pragma unroll
  for (int mt = 0; mt < 4; ++mt)
#pragma unroll
    for (int nt = 0; nt < 4; ++nt) {
      if constexpr (EPI == 2) {
        // C^T tile: row of D = out col, col of D = out row (token)
        int gm  = tm + wr * 64 + mt * 16 + l16;        // token
        int gn0 = tn + wc * 64 + nt * 16 + quad * 4;   // col base
        float4 bv = *(const float4*)&bias[gn0];
        float4 o;
        o.x = acc[mt][nt][0] + bv.x;
        o.y = acc[mt][nt][1] + bv.y;
        o.z = acc[mt][nt][2] + bv.z;
        o.w = acc[mt][nt][3] + bv.w;
        *(float4*)&((float*)Cout)[(size_t)gm * 1024 + gn0] = o;
      } else if constexpr (EPI == 0) {
        int gm = tm + wr * 64 + mt * 16 + l16;         // token
        int f0 = tn + wc * 64 + nt * 16 + quad * 4;    // 0..2047 (Q|K)
        int which = f0 >> 10, col = f0 & 1023;
        int b = gm >> 11, nn = gm & 2047, h = col >> 6, d = col & 63;
        float s = (which == 0) ? SCALE_LOG2E : 1.0f;
        bf16x4 o;
        o[0] = (__bf16)(acc[mt][nt][0] * s);
        o[1] = (__bf16)(acc[mt][nt][1] * s);
        o[2] = (__bf16)(acc[mt][nt][2] * s);
        o[3] = (__bf16)(acc[mt][nt][3] * s);
        __bf16* op = (__bf16*)Cout + (size_t)which * (BATCH * SEQ * (size_t)D_MODEL) +
                     ((size_t)(b * NH + h) * SEQ + nn) * HD + d;
        *(bf16x4*)op = o;
      } else {   // EPI 1: V transposed, natural orientation
        int gm0 = tm + wr * 64 + mt * 16 + quad * 4;   // token base
        int gn  = tn + wc * 64 + nt * 16 + l16;        // feature 0..1023
        int b = gm0 >> 11, nn0 = gm0 & 2047, h = gn >> 6, d = gn & 63;
        bf16x4 o;
        o[0] = (__bf16)acc[mt][nt][0];
        o[1] = (__bf16)acc[mt][nt][1];
        o[2] = (__bf16)acc[mt][nt][2];
        o[3] = (__bf16)acc[mt][nt][3];
        __bf16* op = (__bf16*)Cout + ((size_t)(b * NH + h) * HD + d) * SEQ + nn0;
        *(bf16x4*)op = o;
      }
    }
}

// ---------------- causal flash attention, register-PV, double-buffered ----
// grid (8, 64), block 256 (4 waves). Block pr handles q-tile pair
// (pr, 15-pr), 128 rows each; wave w owns rows tile*128+w*32 .. +32.
// S^T = mfma_16x16x32(Kfrag, Qfrag): lane holds S[q=l16][k=quad*4+i] -- this
// is EXACTLY the A-operand layout of mfma_f32_16x16x16_bf16 (k=quad*4+j), so
// PV runs straight from registers: no P LDS round-trip at all.
// V staged with XOR swizzle (unit = d*8 + ((k>>3)^(d&7))) so the b64 B-frag
// reads are bank-conflict-free. K/V double-buffered: 1 barrier/iter,
// prefetch of iter+1 overlaps compute of iter.
// (R1's K-swizzle REVERTED: it cut bank conflicts 4.8M->3.2M but cost ~8%
//  wall time -- the permuted lane->global map hurt the staging stream.)
__global__ __launch_bounds__(256, 2) void attn(const __bf16* __restrict__ Q,
                                               const __bf16* __restrict__ K,
                                               const __bf16* __restrict__ Vt,
                                               __bf16* __restrict__ ctx) {
  const int tid = threadIdx.x;
  const int lane = tid & 63, w = tid >> 6;
  const int quad = lane >> 4, l16 = lane & 15;
  const int pr = blockIdx.x;            // 0..7
  const int bh = blockIdx.y;
  const int tile0 = pr, tile1 = 15 - pr;
  const __bf16* qb = Q + (size_t)bh * SEQ * HD;
  const __bf16* kb = K + (size_t)bh * SEQ * HD;
  const __bf16* vb = Vt + (size_t)bh * HD * SEQ;

  __shared__ __bf16 KsAll[2 * 4096];   // [buf][half*2048 + key*32 + d]
  __shared__ __bf16 VsAll[2 * 4096];   // [buf][d*64 + ((k>>3)^(d&7))*8 + (k&7)]

  const int qmin[2] = {tile0 * 128 + w * 32, tile1 * 128 + w * 32};

  // Q fragments (B-operand, scale pre-folded), both phases
  bf16x8 aq[2][2][2];
#pragma unroll
  for (int p = 0; p < 2; ++p)
#pragma unroll
    for (int qq = 0; qq < 2; ++qq)
#pragma unroll
      for (int kk = 0; kk < 2; ++kk)
        aq[p][qq][kk] = *(const bf16x8*)(qb + (size_t)(qmin[p] + qq * 16 + l16) * HD +
                                         kk * 32 + quad * 8);

  f32x4 acc[2][2][4] = {};   // [phase][qq][cd] rows q=quad*4+i, cols d=cd*16+l16
  float lsum[2][2] = {};     // [phase][qq] per-lane partial for q-col = l16

  // staging decode. K (R3 pattern): unit u -> key r=(u>>2)&63, half h=u>>8,
  // elem e=(u&3)*8. V (swizzled): unit u -> d=u>>3, kc=(u&7)^(d&7).
  const int u0 = w * 128 + lane;
  const int u1 = u0 + 64;
  const int kOffG0 = ((u0 >> 2) & 63) * HD + (u0 >> 8) * 32 + (u0 & 3) * 8;
  const int kOffG1 = ((u1 >> 2) & 63) * HD + (u1 >> 8) * 32 + (u1 & 3) * 8;
  const int vd0 = u0 >> 3, vd1 = u1 >> 3;
  const int vOffG0 = vd0 * SEQ + (((u0 & 7) ^ (vd0 & 7)) * 8);
  const int vOffG1 = vd1 * SEQ + (((u1 & 7) ^ (vd1 & 7)) * 8);

  auto stage = [&](int k0s, int bufsel) {
    __bf16* Kb = KsAll + bufsel * 4096;
    __bf16* Vb = VsAll + bufsel * 4096;
    gld_lds16(kb + (size_t)k0s * HD + kOffG0, Kb + u0 * 8);
    gld_lds16(kb + (size_t)k0s * HD + kOffG1, Kb + u1 * 8);
    gld_lds16(vb + k0s + vOffG0, Vb + u0 * 8);
    gld_lds16(vb + k0s + vOffG1, Vb + u1 * 8);
  };

  const int nIter = 2 * tile1 + 2;
  stage(0, 0);

  for (int it = 0; it < nIter; ++it) {
    __syncthreads();   // buf[it&1] staged; all waves done with buf[(it+1)&1]
    if (it + 1 < nIter) stage((it + 1) * 64, (it + 1) & 1);

    const int k0 = it * 64;
    if (k0 <= qmin[1] + 31) {   // phase-1 active (superset of phase-0 range)
      const __bf16* Kb = KsAll + (it & 1) * 4096;
      const __bf16* Vb = VsAll + (it & 1) * 4096;

      bf16x8 bk[4][2];          // A-operand K frags: rows = keys
#pragma unroll
      for (int kt = 0; kt < 4; ++kt)
#pragma unroll
        for (int kk = 0; kk < 2; ++kk)
          bk[kt][kk] = *(const bf16x8*)&Kb[kk * 2048 + (kt * 16 + l16) * 32 + quad * 8];

      // V B-frags for K=16 PV: vf[kt][cd] = V[k=kt*16+quad*4 ..+3][d=cd*16+l16]
      short4_t vf[4][4];
#pragma unroll
      for (int kt = 0; kt < 4; ++kt)
#pragma unroll
        for (int cd = 0; cd < 4; ++cd)
          vf[kt][cd] = *(const short4_t*)&Vb[(cd * 16 + l16) * 64 +
                                             (((kt * 2 + (quad >> 1)) ^ (l16 & 7)) * 8) +
                                             (quad & 1) * 4];

#pragma unroll
      for (int p = 0; p < 2; ++p) {
        if (k0 > qmin[p] + 31) continue;
        // S^T[k][q]: rows k = k0+kt*16+quad*4+i, cols q = qmin[p]+qq*16+l16
        f32x4 St[4][2] = {};
#pragma unroll
        for (int kt = 0; kt < 4; ++kt)
#pragma unroll
          for (int qq = 0; qq < 2; ++qq) {
            St[kt][qq] = __builtin_amdgcn_mfma_f32_16x16x32_bf16(
                bk[kt][0], aq[p][qq][0], St[kt][qq], 0, 0, 0);
            St[kt][qq] = __builtin_amdgcn_mfma_f32_16x16x32_bf16(
                bk[kt][1], aq[p][qq][1], St[kt][qq], 0, 0, 0);
          }
        const bool full = (k0 + 63 <= qmin[p]);
#pragma unroll
        for (int kt = 0; kt < 4; ++kt)
#pragma unroll
          for (int qq = 0; qq < 2; ++qq) {
            float e0 = __builtin_amdgcn_exp2f(St[kt][qq][0]);
            float e1 = __builtin_amdgcn_exp2f(St[kt][qq][1]);
            float e2 = __builtin_amdgcn_exp2f(St[kt][qq][2]);
            float e3 = __builtin_amdgcn_exp2f(St[kt][qq][3]);
            if (!full) {
              int kg = k0 + kt * 16 + quad * 4;
              int qg = qmin[p] + qq * 16 + l16;
              if (kg + 0 > qg) e0 = 0.f;
              if (kg + 1 > qg) e1 = 0.f;
              if (kg + 2 > qg) e2 = 0.f;
              if (kg + 3 > qg) e3 = 0.f;
            }
            lsum[p][qq] += (e0 + e1) + (e2 + e3);
            short4_t ap;
            ap[0] = __builtin_bit_cast(short, (__bf16)e0);
            ap[1] = __builtin_bit_cast(short, (__bf16)e1);
            ap[2] = __builtin_bit_cast(short, (__bf16)e2);
            ap[3] = __builtin_bit_cast(short, (__bf16)e3);
            // PV straight from registers: O[q][d] tiles over d
#pragma unroll
            for (int cd = 0; cd < 4; ++cd)
              acc[p][qq][cd] = __builtin_amdgcn_mfma_f32_16x16x16bf16_1k(
                  ap, vf[kt][cd], acc[p][qq][cd], 0, 0, 0);
          }
      }
    }
  }

  const int bb = bh >> 4, hh = bh & 15;
#pragma unroll
  for (int p = 0; p < 2; ++p) {
#pragma unroll
    for (int qq = 0; qq < 2; ++qq) {
      float s = lsum[p][qq];
      s += __shfl_xor(s, 16);
      s += __shfl_xor(s, 32);   // all lanes: total for q-col = own l16
      float rinv[4];
#pragma unroll
      for (int i = 0; i < 4; ++i)
        rinv[i] = 1.0f / __shfl(s, (lane & 48) + quad * 4 + i);
#pragma unroll
      for (int c = 0; c < 4; ++c)
#pragma unroll
        for (int i = 0; i < 4; ++i) {
          int q = qmin[p] + qq * 16 + quad * 4 + i;
          float o = acc[p][qq][c][i] * rinv[i];
          ctx[((size_t)(bb * SEQ + q)) * D_MODEL + hh * HD + c * 16 + l16] = (__bf16)o;
        }
    }
  }
}

extern "C" void kernel_launch(void* const* d_in, const int* in_sizes, int n_in,
                              void* d_out, int out_size, void* d_ws, size_t ws_size,
                              hipStream_t stream) {
  const float* x  = (const float*)d_in[0];
  const float* Wq = (const float*)d_in[1];
  const float* Wk = (const float*)d_in[2];
  const float* Wv = (const float*)d_in[3];
  const float* Wo = (const float*)d_in[4];
  const float* bo = (const float*)d_in[5];
  float* out = (float*)d_out;
  char* ws = (char*)d_ws;
  const size_t MB = 1024 * 1024;
  __bf16* xb   = (__bf16*)(ws);             // 16 MB; reused as ctx after attn
  __bf16* Wqkv = (__bf16*)(ws + 16 * MB);   // 6 MB: Wqt|Wkt|Wvt contiguous
  __bf16* Wot  = (__bf16*)(ws + 22 * MB);   // 2 MB
  __bf16* Qh   = (__bf16*)(ws + 24 * MB);   // 16 MB [b,h,n,d], pre-scaled
  __bf16* Kh   = (__bf16*)(ws + 40 * MB);   // 16 MB [b,h,n,d]
  __bf16* Vth  = (__bf16*)(ws + 56 * MB);   // 16 MB [b,h,d,n]
  __bf16* ctx  = xb;                        // alias: xb dead after QKV GEMM

  cvt_x<<<MROWS * D_MODEL / (256 * 4), 256, 0, stream>>>(x, xb);
  dim3 tb(32, 8);
  cvt_wt<<<dim3(32, 32), tb, 0, stream>>>(Wq, Wqkv);
  cvt_wt<<<dim3(32, 32), tb, 0, stream>>>(Wk, Wqkv + 1024 * 1024);
  cvt_wt<<<dim3(32, 32), tb, 0, stream>>>(Wv, Wqkv + 2 * 1024 * 1024);
  cvt_wt<<<dim3(32, 32), tb, 0, stream>>>(Wo, Wot);

  // QK projection (swapped-operand epilogue), then V projection (natural)
  gemm_bt<0><<<dim3(16, 64), 256, 0, stream>>>(xb, Wqkv, nullptr, Qh);
  gemm_bt<1><<<dim3(8, 64), 256, 0, stream>>>(xb, Wqkv + 2 * 1024 * 1024, nullptr, Vth);

  attn<<<dim3(8, BATCH * NH), 256, 0, stream>>>(Qh, Kh, Vth, ctx);

  gemm_bt<2><<<dim3(8, 64), 256, 0, stream>>>(ctx, Wot, bo, out);
}

// Round 3
// 282.520 us; speedup vs baseline: 1.0060x; 1.0039x over previous
//
#include <hip/hip_runtime.h>
#include <hip/hip_bf16.h>
#include <math.h>

typedef __attribute__((ext_vector_type(8))) __bf16 bf16x8;
typedef __attribute__((ext_vector_type(4))) __bf16 bf16x4;
typedef __attribute__((ext_vector_type(4))) float f32x4;
typedef __attribute__((ext_vector_type(4))) short short4_t;

#define D_MODEL 1024
#define SEQ     2048
#define BATCH   4
#define NH      16
#define HD      64
#define MROWS   (BATCH * SEQ)   // 8192

// 0.125 (1/sqrt(64)) * log2(e): folded into Q at the QKV-GEMM epilogue
#define SCALE_LOG2E 0.18033688011112042f

__device__ __forceinline__ void gld_lds16(const __bf16* g, __bf16* l) {
  __builtin_amdgcn_global_load_lds(
      (const __attribute__((address_space(1))) void*)g,
      (__attribute__((address_space(3))) void*)l, 16, 0, 0);
}

// ---------------- convert x: fp32 -> bf16, vectorized ----------------
__global__ __launch_bounds__(256) void cvt_x(const float* __restrict__ in,
                                             __bf16* __restrict__ out) {
  int i = (blockIdx.x * 256 + threadIdx.x) * 4;
  float4 f = *(const float4*)(in + i);
  bf16x4 o;
  o.x = (__bf16)f.x; o.y = (__bf16)f.y; o.z = (__bf16)f.z; o.w = (__bf16)f.w;
  *(bf16x4*)(out + i) = o;
}

// -- convert + transpose weights: fp32 [K][N] -> bf16 [N][K], all 4 in one
// dispatch (blockIdx.z selects the weight; saves 3 launch overheads) --
__global__ __launch_bounds__(256) void cvt_wt4(const float* __restrict__ W0,
                                               const float* __restrict__ W1,
                                               const float* __restrict__ W2,
                                               const float* __restrict__ W3,
                                               __bf16* __restrict__ Wqkv,
                                               __bf16* __restrict__ Wot) {
  __shared__ __bf16 t[32][33];
  int tx = threadIdx.x, ty = threadIdx.y;   // block (32,8)
  int z = blockIdx.z;
  const float* W = (z == 0) ? W0 : (z == 1) ? W1 : (z == 2) ? W2 : W3;
  __bf16* Wt = (z < 3) ? (Wqkv + (size_t)z * 1024 * 1024) : Wot;
  int n0 = blockIdx.x * 32, k0 = blockIdx.y * 32;
#pragma unroll
  for (int j = 0; j < 32; j += 8)
    t[ty + j][tx] = (__bf16)W[(size_t)(k0 + ty + j) * D_MODEL + n0 + tx];
  __syncthreads();
#pragma unroll
  for (int j = 0; j < 32; j += 8)
    Wt[(size_t)(n0 + ty + j) * D_MODEL + k0 + tx] = t[tx][ty + j];
}

// ---------------- GEMM: C[M,N] = A[M,K] @ Bt[N,K]^T  (bf16)
// 256x128 tile, 8 waves (wave grid 4M x 2N, each wave = m97's proven 64x64 /
// 4x4-acc inner loop), BK=64 run as two K-major BK=32 sub-tiles so the frag
// addressing (row*32 + quad*8) is byte-identical to the m97 pattern (same
// bank profile). Double-buffered LDS (2 x 48 KB = 96 KB), ONE full
// __syncthreads per K-tile: stage(t+1 -> buf^1), compute(buf) 32 MFMA/wave,
// barrier (compiler vmcnt(0)+lgkmcnt(0) drain -- the prefetch had the whole
// 32-MFMA phase to fly). 4x the per-barrier MFMA amortization of the R0
// structure; sync logic identical to R1's verified-safe pattern.
// Operand-swap trick: passing (Bfrag, Afrag) to MFMA yields C^T tiles, so a
// lane holds 4 CONSECUTIVE minor-dim outputs -> vector stores. Orientation
// per output layout:
// EPI 0 (SWAP): QK, N=2048. lane: token=l16, d=quad*4+i -> bf16x4 to [b,h,n,d]
//               (which = Q or K per 1024-col block; Q pre-scaled)
// EPI 1 (no swap): V, N=1024. lane: d=l16, token=quad*4+i -> bf16x4 to [b,h,d,n]
// EPI 2 (SWAP): proj, N=1024 fp32. lane: row=l16, col=quad*4+i -> float4+bias
template <int EPI>
__global__ __launch_bounds__(512, 2) void gemm_bt(const __bf16* __restrict__ A,
                                                  const __bf16* __restrict__ Bt,
                                                  const float* __restrict__ bias,
                                                  void* __restrict__ Cout) {
  constexpr int Kd = 1024;
  constexpr int NT = Kd / 64;          // 16 K-tiles of BK=64
  constexpr bool SWAP = (EPI != 1);
  __shared__ __bf16 As[2][256 * 64];   // [buf][kk*8192 + row*32 + c8*8]
  __shared__ __bf16 Bs[2][128 * 64];   // [buf][kk*4096 + row*32 + c8*8]
  const int tid = threadIdx.x;
  const int lane = tid & 63;
  const int w = tid >> 6;              // 0..7
  const int quad = lane >> 4, l16 = lane & 15;
  const int wr = w >> 1, wc = w & 1;   // 4M x 2N wave grid
  const int tm = blockIdx.y * 256, tn = blockIdx.x * 128;

  f32x4 acc[4][4] = {};

  // staging decode: unit u (16B) -> kk = u>>10 (A) / u>>9 (B), row, col8.
  // LDS dest linear at u*8 elems (wave-uniform base + lane*16B).
  const __bf16* pA[4]; int dA[4];
#pragma unroll
  for (int j = 0; j < 4; ++j) {
    int u = j * 512 + tid;
    int r = (u >> 2) & 255;
    int ko = (u >> 10) * 32 + (u & 3) * 8;
    pA[j] = A + (size_t)(tm + r) * Kd + ko;
    dA[j] = u * 8;
  }
  const __bf16* pB[2]; int dB[2];
#pragma unroll
  for (int j = 0; j < 2; ++j) {
    int u = j * 512 + tid;
    int r = (u >> 2) & 127;
    int ko = (u >> 9) * 32 + (u & 3) * 8;
    pB[j] = Bt + (size_t)(tn + r) * Kd + ko;
    dB[j] = u * 8;
  }

  auto stageg = [&](int k0s, int bf) {
#pragma unroll
    for (int j = 0; j < 4; ++j) gld_lds16(pA[j] + k0s, &As[bf][dA[j]]);
#pragma unroll
    for (int j = 0; j < 2; ++j) gld_lds16(pB[j] + k0s, &Bs[bf][dB[j]]);
  };

  // prologue: stage K-tile 0, publish
  stageg(0, 0);
  __syncthreads();

  int buf = 0;
#pragma unroll 2
  for (int t = 0; t < NT; ++t) {
    if (t + 1 < NT) stageg((t + 1) * 64, buf ^ 1);
#pragma unroll
    for (int kk = 0; kk < 2; ++kk) {
      bf16x8 af[4], bfr[4];
#pragma unroll
      for (int x = 0; x < 4; ++x) {
        af[x]  = *(const bf16x8*)&As[buf][kk * 8192 + (wr * 64 + x * 16 + l16) * 32 + quad * 8];
        bfr[x] = *(const bf16x8*)&Bs[buf][kk * 4096 + (wc * 64 + x * 16 + l16) * 32 + quad * 8];
      }
#pragma unroll
      for (int mt = 0; mt < 4; ++mt)
#pragma unroll
        for (int nt = 0; nt < 4; ++nt) {
          if constexpr (SWAP)
            acc[mt][nt] = __builtin_amdgcn_mfma_f32_16x16x32_bf16(
                bfr[nt], af[mt], acc[mt][nt], 0, 0, 0);
          else
            acc[mt][nt] = __builtin_amdgcn_mfma_f32_16x16x32_bf16(
                af[mt], bfr[nt], acc[mt][nt], 0, 0, 0);
        }
    }
    // one barrier per K-tile: drains this tile's prefetch and fences all
    // waves' reads of buf before the next iteration overwrites it.
    __syncthreads();
    buf ^= 1;
  }

#pragma unroll
  for (int mt = 0; mt < 4; ++mt)
#pragma unroll
    for (int nt = 0; nt < 4; ++nt) {
      if constexpr (EPI == 2) {
        // C^T tile: row of D = out col, col of D = out row (token)
        int gm  = tm + wr * 64 + mt * 16 + l16;        // token
        int gn0 = tn + wc * 64 + nt * 16 + quad * 4;   // col base
        float4 bv = *(const float4*)&bias[gn0];
        float4 o;
        o.x = acc[mt][nt][0] + bv.x;
        o.y = acc[mt][nt][1] + bv.y;
        o.z = acc[mt][nt][2] + bv.z;
        o.w = acc[mt][nt][3] + bv.w;
        *(float4*)&((float*)Cout)[(size_t)gm * 1024 + gn0] = o;
      } else if constexpr (EPI == 0) {
        int gm = tm + wr * 64 + mt * 16 + l16;         // token
        int f0 = tn + wc * 64 + nt * 16 + quad * 4;    // 0..2047 (Q|K)
        int which = f0 >> 10, col = f0 & 1023;
        int b = gm >> 11, nn = gm & 2047, h = col >> 6, d = col & 63;
        float s = (which == 0) ? SCALE_LOG2E : 1.0f;
        bf16x4 o;
        o[0] = (__bf16)(acc[mt][nt][0] * s);
        o[1] = (__bf16)(acc[mt][nt][1] * s);
        o[2] = (__bf16)(acc[mt][nt][2] * s);
        o[3] = (__bf16)(acc[mt][nt][3] * s);
        __bf16* op = (__bf16*)Cout + (size_t)which * (BATCH * SEQ * (size_t)D_MODEL) +
                     ((size_t)(b * NH + h) * SEQ + nn) * HD + d;
        *(bf16x4*)op = o;
      } else {   // EPI 1: V transposed, natural orientation
        int gm0 = tm + wr * 64 + mt * 16 + quad * 4;   // token base
        int gn  = tn + wc * 64 + nt * 16 + l16;        // feature 0..1023
        int b = gm0 >> 11, nn0 = gm0 & 2047, h = gn >> 6, d = gn & 63;
        bf16x4 o;
        o[0] = (__bf16)acc[mt][nt][0];
        o[1] = (__bf16)acc[mt][nt][1];
        o[2] = (__bf16)acc[mt][nt][2];
        o[3] = (__bf16)acc[mt][nt][3];
        __bf16* op = (__bf16*)Cout + ((size_t)(b * NH + h) * HD + d) * SEQ + nn0;
        *(bf16x4*)op = o;
      }
    }
}

// ---------------- causal flash attention, register-PV, double-buffered ----
// grid (8, 64), block 256 (4 waves). Block pr handles q-tile pair
// (pr, 15-pr), 128 rows each; wave w owns rows tile*128+w*32 .. +32.
// S^T = mfma_16x16x32(Kfrag, Qfrag): lane holds S[q=l16][k=quad*4+i] -- this
// is EXACTLY the A-operand layout of mfma_f32_16x16x16_bf16 (k=quad*4+j), so
// PV runs straight from registers: no P LDS round-trip at all.
// V staged with XOR swizzle (unit = d*8 + ((k>>3)^(d&7))) so the b64 B-frag
// reads are bank-conflict-free. K/V double-buffered: 1 barrier/iter,
// prefetch of iter+1 overlaps compute of iter.
// (R1's K-swizzle REVERTED: it cut bank conflicts 4.8M->3.2M but cost ~8%
//  wall time -- the permuted lane->global map hurt the staging stream.)
__global__ __launch_bounds__(256, 2) void attn(const __bf16* __restrict__ Q,
                                               const __bf16* __restrict__ K,
                                               const __bf16* __restrict__ Vt,
                                               __bf16* __restrict__ ctx) {
  const int tid = threadIdx.x;
  const int lane = tid & 63, w = tid >> 6;
  const int quad = lane >> 4, l16 = lane & 15;
  const int pr = blockIdx.x;            // 0..7
  const int bh = blockIdx.y;
  const int tile0 = pr, tile1 = 15 - pr;
  const __bf16* qb = Q + (size_t)bh * SEQ * HD;
  const __bf16* kb = K + (size_t)bh * SEQ * HD;
  const __bf16* vb = Vt + (size_t)bh * HD * SEQ;

  __shared__ __bf16 KsAll[2 * 4096];   // [buf][half*2048 + key*32 + d]
  __shared__ __bf16 VsAll[2 * 4096];   // [buf][d*64 + ((k>>3)^(d&7))*8 + (k&7)]

  const int qmin[2] = {tile0 * 128 + w * 32, tile1 * 128 + w * 32};

  // Q fragments (B-operand, scale pre-folded), both phases
  bf16x8 aq[2][2][2];
#pragma unroll
  for (int p = 0; p < 2; ++p)
#pragma unroll
    for (int qq = 0; qq < 2; ++qq)
#pragma unroll
      for (int kk = 0; kk < 2; ++kk)
        aq[p][qq][kk] = *(const bf16x8*)(qb + (size_t)(qmin[p] + qq * 16 + l16) * HD +
                                         kk * 32 + quad * 8);

  f32x4 acc[2][2][4] = {};   // [phase][qq][cd] rows q=quad*4+i, cols d=cd*16+l16
  float lsum[2][2] = {};     // [phase][qq] per-lane partial for q-col = l16

  // staging decode. K (R3 pattern): unit u -> key r=(u>>2)&63, half h=u>>8,
  // elem e=(u&3)*8. V (swizzled): unit u -> d=u>>3, kc=(u&7)^(d&7).
  const int u0 = w * 128 + lane;
  const int u1 = u0 + 64;
  const int kOffG0 = ((u0 >> 2) & 63) * HD + (u0 >> 8) * 32 + (u0 & 3) * 8;
  const int kOffG1 = ((u1 >> 2) & 63) * HD + (u1 >> 8) * 32 + (u1 & 3) * 8;
  const int vd0 = u0 >> 3, vd1 = u1 >> 3;
  const int vOffG0 = vd0 * SEQ + (((u0 & 7) ^ (vd0 & 7)) * 8);
  const int vOffG1 = vd1 * SEQ + (((u1 & 7) ^ (vd1 & 7)) * 8);

  auto stage = [&](int k0s, int bufsel) {
    __bf16* Kb = KsAll + bufsel * 4096;
    __bf16* Vb = VsAll + bufsel * 4096;
    gld_lds16(kb + (size_t)k0s * HD + kOffG0, Kb + u0 * 8);
    gld_lds16(kb + (size_t)k0s * HD + kOffG1, Kb + u1 * 8);
    gld_lds16(vb + k0s + vOffG0, Vb + u0 * 8);
    gld_lds16(vb + k0s + vOffG1, Vb + u1 * 8);
  };

  const int nIter = 2 * tile1 + 2;
  stage(0, 0);

  for (int it = 0; it < nIter; ++it) {
    __syncthreads();   // buf[it&1] staged; all waves done with buf[(it+1)&1]
    if (it + 1 < nIter) stage((it + 1) * 64, (it + 1) & 1);

    const int k0 = it * 64;
    if (k0 <= qmin[1] + 31) {   // phase-1 active (superset of phase-0 range)
      const __bf16* Kb = KsAll + (it & 1) * 4096;
      const __bf16* Vb = VsAll + (it & 1) * 4096;

      bf16x8 bk[4][2];          // A-operand K frags: rows = keys
#pragma unroll
      for (int kt = 0; kt < 4; ++kt)
#pragma unroll
        for (int kk = 0; kk < 2; ++kk)
          bk[kt][kk] = *(const bf16x8*)&Kb[kk * 2048 + (kt * 16 + l16) * 32 + quad * 8];

      // V B-frags for K=16 PV: vf[kt][cd] = V[k=kt*16+quad*4 ..+3][d=cd*16+l16]
      short4_t vf[4][4];
#pragma unroll
      for (int kt = 0; kt < 4; ++kt)
#pragma unroll
        for (int cd = 0; cd < 4; ++cd)
          vf[kt][cd] = *(const short4_t*)&Vb[(cd * 16 + l16) * 64 +
                                             (((kt * 2 + (quad >> 1)) ^ (l16 & 7)) * 8) +
                                             (quad & 1) * 4];

#pragma unroll
      for (int p = 0; p < 2; ++p) {
        if (k0 > qmin[p] + 31) continue;
        // S^T[k][q]: rows k = k0+kt*16+quad*4+i, cols q = qmin[p]+qq*16+l16
        f32x4 St[4][2] = {};
#pragma unroll
        for (int kt = 0; kt < 4; ++kt)
#pragma unroll
          for (int qq = 0; qq < 2; ++qq) {
            St[kt][qq] = __builtin_amdgcn_mfma_f32_16x16x32_bf16(
                bk[kt][0], aq[p][qq][0], St[kt][qq], 0, 0, 0);
            St[kt][qq] = __builtin_amdgcn_mfma_f32_16x16x32_bf16(
                bk[kt][1], aq[p][qq][1], St[kt][qq], 0, 0, 0);
          }
        const bool full = (k0 + 63 <= qmin[p]);
#pragma unroll
        for (int kt = 0; kt < 4; ++kt)
#pragma unroll
          for (int qq = 0; qq < 2; ++qq) {
            float e0 = __builtin_amdgcn_exp2f(St[kt][qq][0]);
            float e1 = __builtin_amdgcn_exp2f(St[kt][qq][1]);
            float e2 = __builtin_amdgcn_exp2f(St[kt][qq][2]);
            float e3 = __builtin_amdgcn_exp2f(St[kt][qq][3]);
            if (!full) {
              int kg = k0 + kt * 16 + quad * 4;
              int qg = qmin[p] + qq * 16 + l16;
              if (kg + 0 > qg) e0 = 0.f;
              if (kg + 1 > qg) e1 = 0.f;
              if (kg + 2 > qg) e2 = 0.f;
              if (kg + 3 > qg) e3 = 0.f;
            }
            lsum[p][qq] += (e0 + e1) + (e2 + e3);
            short4_t ap;
            ap[0] = __builtin_bit_cast(short, (__bf16)e0);
            ap[1] = __builtin_bit_cast(short, (__bf16)e1);
            ap[2] = __builtin_bit_cast(short, (__bf16)e2);
            ap[3] = __builtin_bit_cast(short, (__bf16)e3);
            // PV straight from registers: O[q][d] tiles over d
#pragma unroll
            for (int cd = 0; cd < 4; ++cd)
              acc[p][qq][cd] = __builtin_amdgcn_mfma_f32_16x16x16bf16_1k(
                  ap, vf[kt][cd], acc[p][qq][cd], 0, 0, 0);
          }
      }
    }
  }

  const int bb = bh >> 4, hh = bh & 15;
#pragma unroll
  for (int p = 0; p < 2; ++p) {
#pragma unroll
    for (int qq = 0; qq < 2; ++qq) {
      float s = lsum[p][qq];
      s += __shfl_xor(s, 16);
      s += __shfl_xor(s, 32);   // all lanes: total for q-col = own l16
      float rinv[4];
#pragma unroll
      for (int i = 0; i < 4; ++i)
        rinv[i] = 1.0f / __shfl(s, (lane & 48) + quad * 4 + i);
#pragma unroll
      for (int c = 0; c < 4; ++c)
#pragma unroll
        for (int i = 0; i < 4; ++i) {
          int q = qmin[p] + qq * 16 + quad * 4 + i;
          float o = acc[p][qq][c][i] * rinv[i];
          ctx[((size_t)(bb * SEQ + q)) * D_MODEL + hh * HD + c * 16 + l16] = (__bf16)o;
        }
    }
  }
}

extern "C" void kernel_launch(void* const* d_in, const int* in_sizes, int n_in,
                              void* d_out, int out_size, void* d_ws, size_t ws_size,
                              hipStream_t stream) {
  const float* x  = (const float*)d_in[0];
  const float* Wq = (const float*)d_in[1];
  const float* Wk = (const float*)d_in[2];
  const float* Wv = (const float*)d_in[3];
  const float* Wo = (const float*)d_in[4];
  const float* bo = (const float*)d_in[5];
  float* out = (float*)d_out;
  char* ws = (char*)d_ws;
  const size_t MB = 1024 * 1024;
  __bf16* xb   = (__bf16*)(ws);             // 16 MB; reused as ctx after attn
  __bf16* Wqkv = (__bf16*)(ws + 16 * MB);   // 6 MB: Wqt|Wkt|Wvt contiguous
  __bf16* Wot  = (__bf16*)(ws + 22 * MB);   // 2 MB
  __bf16* Qh   = (__bf16*)(ws + 24 * MB);   // 16 MB [b,h,n,d], pre-scaled
  __bf16* Kh   = (__bf16*)(ws + 40 * MB);   // 16 MB [b,h,n,d]
  __bf16* Vth  = (__bf16*)(ws + 56 * MB);   // 16 MB [b,h,d,n]
  __bf16* ctx  = xb;                        // alias: xb dead after QKV GEMM

  cvt_x<<<MROWS * D_MODEL / (256 * 4), 256, 0, stream>>>(x, xb);
  cvt_wt4<<<dim3(32, 32, 4), dim3(32, 8), 0, stream>>>(Wq, Wk, Wv, Wo, Wqkv, Wot);

  // QK projection (swapped-operand epilogue), then V projection (natural)
  gemm_bt<0><<<dim3(16, 32), 512, 0, stream>>>(xb, Wqkv, nullptr, Qh);
  gemm_bt<1><<<dim3(8, 32), 512, 0, stream>>>(xb, Wqkv + 2 * 1024 * 1024, nullptr, Vth);

  attn<<<dim3(8, BATCH * NH), 256, 0, stream>>>(Qh, Kh, Vth, ctx);

  gemm_bt<2><<<dim3(8, 32), 512, 0, stream>>>(ctx, Wot, bo, out);
}

// Round 5
// 263.823 us; speedup vs baseline: 1.0773x; 1.0709x over previous
//
#include <hip/hip_runtime.h>
#include <hip/hip_bf16.h>
#include <math.h>

typedef __attribute__((ext_vector_type(8))) __bf16 bf16x8;
typedef __attribute__((ext_vector_type(4))) __bf16 bf16x4;
typedef __attribute__((ext_vector_type(4))) float f32x4;
typedef __attribute__((ext_vector_type(4))) short short4_t;

#define D_MODEL 1024
#define SEQ     2048
#define BATCH   4
#define NH      16
#define HD      64
#define MROWS   (BATCH * SEQ)   // 8192

// 0.125 (1/sqrt(64)) * log2(e): folded into Q at the QKV-GEMM epilogue
#define SCALE_LOG2E 0.18033688011112042f

__device__ __forceinline__ void gld_lds16(const __bf16* g, __bf16* l) {
  __builtin_amdgcn_global_load_lds(
      (const __attribute__((address_space(1))) void*)g,
      (__attribute__((address_space(3))) void*)l, 16, 0, 0);
}

// ---------------- convert x: fp32 -> bf16, vectorized ----------------
__global__ __launch_bounds__(256) void cvt_x(const float* __restrict__ in,
                                             __bf16* __restrict__ out) {
  int i = (blockIdx.x * 256 + threadIdx.x) * 4;
  float4 f = *(const float4*)(in + i);
  bf16x4 o;
  o.x = (__bf16)f.x; o.y = (__bf16)f.y; o.z = (__bf16)f.z; o.w = (__bf16)f.w;
  *(bf16x4*)(out + i) = o;
}

// -- convert + transpose weights: fp32 [K][N] -> bf16 [N][K], all 4 in one
// dispatch (blockIdx.z selects the weight; saves 3 launch overheads) --
__global__ __launch_bounds__(256) void cvt_wt4(const float* __restrict__ W0,
                                               const float* __restrict__ W1,
                                               const float* __restrict__ W2,
                                               const float* __restrict__ W3,
                                               __bf16* __restrict__ Wqkv,
                                               __bf16* __restrict__ Wot) {
  __shared__ __bf16 t[32][33];
  int tx = threadIdx.x, ty = threadIdx.y;   // block (32,8)
  int z = blockIdx.z;
  const float* W = (z == 0) ? W0 : (z == 1) ? W1 : (z == 2) ? W2 : W3;
  __bf16* Wt = (z < 3) ? (Wqkv + (size_t)z * 1024 * 1024) : Wot;
  int n0 = blockIdx.x * 32, k0 = blockIdx.y * 32;
#pragma unroll
  for (int j = 0; j < 32; j += 8)
    t[ty + j][tx] = (__bf16)W[(size_t)(k0 + ty + j) * D_MODEL + n0 + tx];
  __syncthreads();
#pragma unroll
  for (int j = 0; j < 32; j += 8)
    Wt[(size_t)(n0 + ty + j) * D_MODEL + k0 + tx] = t[tx][ty + j];
}

// ---------------- GEMM: C[M,N] = A[M,K] @ Bt[N,K]^T  (bf16, m97 structure)
// R0 structure restored EXACTLY: single-buffer LDS, 2 barriers/K-step,
// 16 KB LDS -> ~4 blocks/CU. R1-R3 showed every intra-block pipelining
// variant (2-phase dbuf, counted-vmcnt depth-2, 256x128/8-wave) loses to
// this at K=1024: inter-BLOCK overlap from high occupancy beats intra-block
// scheduling, and bigger LDS cuts blocks/CU (m132 lesson).
// Operand-swap trick: passing (Bfrag, Afrag) to MFMA yields C^T tiles, so a
// lane holds 4 CONSECUTIVE minor-dim outputs -> vector stores (b64/b128)
// instead of 4 scalar stores. Orientation chosen per output layout:
// EPI 0 (SWAP): QK, N=2048. lane: token=l16, d=quad*4+i -> bf16x4 to [b,h,n,d]
//               (which = Q or K per 1024-col block; Q pre-scaled)
// EPI 1 (no swap): V, N=1024. lane: d=l16, token=quad*4+i -> bf16x4 to [b,h,d,n]
// EPI 2 (SWAP): proj, N=1024 fp32. lane: row=l16, col=quad*4+i -> float4+bias
template <int EPI>
__global__ __launch_bounds__(256) void gemm_bt(const __bf16* __restrict__ A,
                                               const __bf16* __restrict__ Bt,
                                               const float* __restrict__ bias,
                                               void* __restrict__ Cout) {
  constexpr int Kd = 1024;
  constexpr bool SWAP = (EPI != 1);
  __shared__ __bf16 As[128 * 32];
  __shared__ __bf16 Bs[128 * 32];
  const int tid = threadIdx.x;
  const int lane = tid & 63;
  const int w = tid >> 6;
  const int quad = lane >> 4, l16 = lane & 15;
  const int wr = w >> 1, wc = w & 1;
  const int tm = blockIdx.y * 128, tn = blockIdx.x * 128;

  f32x4 acc[4][4] = {};

  const int u0 = (w * 2) * 64 + lane;
  const int u1 = u0 + 64;
  const int rA0 = u0 >> 2, kofs0 = (u0 & 3) * 8;
  const int rA1 = u1 >> 2, kofs1 = (u1 & 3) * 8;
  const __bf16* gA0 = A + (size_t)(tm + rA0) * Kd + kofs0;
  const __bf16* gA1 = A + (size_t)(tm + rA1) * Kd + kofs1;
  const __bf16* gB0 = Bt + (size_t)(tn + rA0) * Kd + kofs0;
  const __bf16* gB1 = Bt + (size_t)(tn + rA1) * Kd + kofs1;
  __bf16* lA0 = As + (w * 2 + 0) * 512;
  __bf16* lA1 = As + (w * 2 + 1) * 512;
  __bf16* lB0 = Bs + (w * 2 + 0) * 512;
  __bf16* lB1 = Bs + (w * 2 + 1) * 512;

  for (int k0 = 0; k0 < Kd; k0 += 32) {
    gld_lds16(gA0 + k0, lA0);
    gld_lds16(gA1 + k0, lA1);
    gld_lds16(gB0 + k0, lB0);
    gld_lds16(gB1 + k0, lB1);
    __syncthreads();
    bf16x8 af[4], bfr[4];
#pragma unroll
    for (int t = 0; t < 4; ++t) {
      af[t]  = *(const bf16x8*)&As[(wr * 64 + t * 16 + l16) * 32 + quad * 8];
      bfr[t] = *(const bf16x8*)&Bs[(wc * 64 + t * 16 + l16) * 32 + quad * 8];
    }
#pragma unroll
    for (int mt = 0; mt < 4; ++mt)
#pragma unroll
      for (int nt = 0; nt < 4; ++nt) {
        if constexpr (SWAP)
          acc[mt][nt] = __builtin_amdgcn_mfma_f32_16x16x32_bf16(
              bfr[nt], af[mt], acc[mt][nt], 0, 0, 0);
        else
          acc[mt][nt] = __builtin_amdgcn_mfma_f32_16x16x32_bf16(
              af[mt], bfr[nt], acc[mt][nt], 0, 0, 0);
      }
    __syncthreads();
  }

#pragma unroll
  for (int mt = 0; mt < 4; ++mt)
#pragma unroll
    for (int nt = 0; nt < 4; ++nt) {
      if constexpr (EPI == 2) {
        // C^T tile: row of D = out col, col of D = out row (token)
        int gm  = tm + wr * 64 + mt * 16 + l16;        // token
        int gn0 = tn + wc * 64 + nt * 16 + quad * 4;   // col base
        float4 bv = *(const float4*)&bias[gn0];
        float4 o;
        o.x = acc[mt][nt][0] + bv.x;
        o.y = acc[mt][nt][1] + bv.y;
        o.z = acc[mt][nt][2] + bv.z;
        o.w = acc[mt][nt][3] + bv.w;
        *(float4*)&((float*)Cout)[(size_t)gm * 1024 + gn0] = o;
      } else if constexpr (EPI == 0) {
        int gm = tm + wr * 64 + mt * 16 + l16;         // token
        int f0 = tn + wc * 64 + nt * 16 + quad * 4;    // 0..2047 (Q|K)
        int which = f0 >> 10, col = f0 & 1023;
        int b = gm >> 11, nn = gm & 2047, h = col >> 6, d = col & 63;
        float s = (which == 0) ? SCALE_LOG2E : 1.0f;
        bf16x4 o;
        o[0] = (__bf16)(acc[mt][nt][0] * s);
        o[1] = (__bf16)(acc[mt][nt][1] * s);
        o[2] = (__bf16)(acc[mt][nt][2] * s);
        o[3] = (__bf16)(acc[mt][nt][3] * s);
        __bf16* op = (__bf16*)Cout + (size_t)which * (BATCH * SEQ * (size_t)D_MODEL) +
                     ((size_t)(b * NH + h) * SEQ + nn) * HD + d;
        *(bf16x4*)op = o;
      } else {   // EPI 1: V transposed, natural orientation
        int gm0 = tm + wr * 64 + mt * 16 + quad * 4;   // token base
        int gn  = tn + wc * 64 + nt * 16 + l16;        // feature 0..1023
        int b = gm0 >> 11, nn0 = gm0 & 2047, h = gn >> 6, d = gn & 63;
        bf16x4 o;
        o[0] = (__bf16)acc[mt][nt][0];
        o[1] = (__bf16)acc[mt][nt][1];
        o[2] = (__bf16)acc[mt][nt][2];
        o[3] = (__bf16)acc[mt][nt][3];
        __bf16* op = (__bf16*)Cout + ((size_t)(b * NH + h) * HD + d) * SEQ + nn0;
        *(bf16x4*)op = o;
      }
    }
}

// ---------------- causal flash attention, register-PV, double-buffered ----
// grid (64, 8), block 256 (4 waves). NEW (R4): bh = blockIdx.x, pr derived
// from blockIdx.y via (0,1,2,3,7,6,5,4). Rationale: workgroup linear id =
// bx + 64*by round-robins across the 8 XCDs, so xcd = bh % 8:
//   (a) XCD load balance -- before, xcd = pr and ALL heaviest blocks (pr=0,
//       32 iters) piled on XCD 0 while XCD 7 got 18-iter blocks (1.78x tail);
//   (b) all 8 blocks sharing one bh's K/V (512 KB, fits 4 MB L2) now land on
//       the SAME XCD -> cross-block L2 reuse instead of 8x re-fetch;
//   (c) resident pairs (id, id+256) get pr and 7-pr: iteration counts sum to
//       a constant 50 -> uniform per-CU load.
// Block pr handles q-tile pair (pr, 15-pr), 128 rows each; wave w owns rows
// tile*128+w*32 .. +32.
// S^T = mfma_16x16x32(Kfrag, Qfrag): lane holds S[q=l16][k=quad*4+i] -- this
// is EXACTLY the A-operand layout of mfma_f32_16x16x16_bf16 (k=quad*4+j), so
// PV runs straight from registers: no P LDS round-trip at all.
// V staged with XOR swizzle (unit = d*8 + ((k>>3)^(d&7))) so the b64 B-frag
// reads are bank-conflict-free. K/V double-buffered: 1 barrier/iter,
// prefetch of iter+1 overlaps compute of iter.
// (R1's K-swizzle REVERTED: cut bank conflicts 4.8M->3.2M but cost ~8%.)
__global__ __launch_bounds__(256, 2) void attn(const __bf16* __restrict__ Q,
                                               const __bf16* __restrict__ K,
                                               const __bf16* __restrict__ Vt,
                                               __bf16* __restrict__ ctx) {
  const int tid = threadIdx.x;
  const int lane = tid & 63, w = tid >> 6;
  const int quad = lane >> 4, l16 = lane & 15;
  const int byy = blockIdx.y;           // 0..7
  const int pr = (byy < 4) ? byy : 11 - byy;   // 0,1,2,3,7,6,5,4
  const int bh = blockIdx.x;            // 0..63
  const int tile0 = pr, tile1 = 15 - pr;
  const __bf16* qb = Q + (size_t)bh * SEQ * HD;
  const __bf16* kb = K + (size_t)bh * SEQ * HD;
  const __bf16* vb = Vt + (size_t)bh * HD * SEQ;

  __shared__ __bf16 KsAll[2 * 4096];   // [buf][half*2048 + key*32 + d]
  __shared__ __bf16 VsAll[2 * 4096];   // [buf][d*64 + ((k>>3)^(d&7))*8 + (k&7)]

  const int qmin[2] = {tile0 * 128 + w * 32, tile1 * 128 + w * 32};

  // Q fragments (B-operand, scale pre-folded), both phases
  bf16x8 aq[2][2][2];
#pragma unroll
  for (int p = 0; p < 2; ++p)
#pragma unroll
    for (int qq = 0; qq < 2; ++qq)
#pragma unroll
      for (int kk = 0; kk < 2; ++kk)
        aq[p][qq][kk] = *(const bf16x8*)(qb + (size_t)(qmin[p] + qq * 16 + l16) * HD +
                                         kk * 32 + quad * 8);

  f32x4 acc[2][2][4] = {};   // [phase][qq][cd] rows q=quad*4+i, cols d=cd*16+l16
  float lsum[2][2] = {};     // [phase][qq] per-lane partial for q-col = l16

  // staging decode. K (R3 pattern): unit u -> key r=(u>>2)&63, half h=u>>8,
  // elem e=(u&3)*8. V (swizzled): unit u -> d=u>>3, kc=(u&7)^(d&7).
  const int u0 = w * 128 + lane;
  const int u1 = u0 + 64;
  const int kOffG0 = ((u0 >> 2) & 63) * HD + (u0 >> 8) * 32 + (u0 & 3) * 8;
  const int kOffG1 = ((u1 >> 2) & 63) * HD + (u1 >> 8) * 32 + (u1 & 3) * 8;
  const int vd0 = u0 >> 3, vd1 = u1 >> 3;
  const int vOffG0 = vd0 * SEQ + (((u0 & 7) ^ (vd0 & 7)) * 8);
  const int vOffG1 = vd1 * SEQ + (((u1 & 7) ^ (vd1 & 7)) * 8);

  auto stage = [&](int k0s, int bufsel) {
    __bf16* Kb = KsAll + bufsel * 4096;
    __bf16* Vb = VsAll + bufsel * 4096;
    gld_lds16(kb + (size_t)k0s * HD + kOffG0, Kb + u0 * 8);
    gld_lds16(kb + (size_t)k0s * HD + kOffG1, Kb + u1 * 8);
    gld_lds16(vb + k0s + vOffG0, Vb + u0 * 8);
    gld_lds16(vb + k0s + vOffG1, Vb + u1 * 8);
  };

  const int nIter = 2 * tile1 + 2;
  stage(0, 0);

  for (int it = 0; it < nIter; ++it) {
    __syncthreads();   // buf[it&1] staged; all waves done with buf[(it+1)&1]
    if (it + 1 < nIter) stage((it + 1) * 64, (it + 1) & 1);

    const int k0 = it * 64;
    if (k0 <= qmin[1] + 31) {   // phase-1 active (superset of phase-0 range)
      const __bf16* Kb = KsAll + (it & 1) * 4096;
      const __bf16* Vb = VsAll + (it & 1) * 4096;

      bf16x8 bk[4][2];          // A-operand K frags: rows = keys
#pragma unroll
      for (int kt = 0; kt < 4; ++kt)
#pragma unroll
        for (int kk = 0; kk < 2; ++kk)
          bk[kt][kk] = *(const bf16x8*)&Kb[kk * 2048 + (kt * 16 + l16) * 32 + quad * 8];

      // V B-frags for K=16 PV: vf[kt][cd] = V[k=kt*16+quad*4 ..+3][d=cd*16+l16]
      short4_t vf[4][4];
#pragma unroll
      for (int kt = 0; kt < 4; ++kt)
#pragma unroll
        for (int cd = 0; cd < 4; ++cd)
          vf[kt][cd] = *(const short4_t*)&Vb[(cd * 16 + l16) * 64 +
                                             (((kt * 2 + (quad >> 1)) ^ (l16 & 7)) * 8) +
                                             (quad & 1) * 4];

#pragma unroll
      for (int p = 0; p < 2; ++p) {
        if (k0 > qmin[p] + 31) continue;
        // S^T[k][q]: rows k = k0+kt*16+quad*4+i, cols q = qmin[p]+qq*16+l16
        f32x4 St[4][2] = {};
#pragma unroll
        for (int kt = 0; kt < 4; ++kt)
#pragma unroll
          for (int qq = 0; qq < 2; ++qq) {
            St[kt][qq] = __builtin_amdgcn_mfma_f32_16x16x32_bf16(
                bk[kt][0], aq[p][qq][0], St[kt][qq], 0, 0, 0);
            St[kt][qq] = __builtin_amdgcn_mfma_f32_16x16x32_bf16(
                bk[kt][1], aq[p][qq][1], St[kt][qq], 0, 0, 0);
          }
        const bool full = (k0 + 63 <= qmin[p]);
#pragma unroll
        for (int kt = 0; kt < 4; ++kt)
#pragma unroll
          for (int qq = 0; qq < 2; ++qq) {
            float e0 = __builtin_amdgcn_exp2f(St[kt][qq][0]);
            float e1 = __builtin_amdgcn_exp2f(St[kt][qq][1]);
            float e2 = __builtin_amdgcn_exp2f(St[kt][qq][2]);
            float e3 = __builtin_amdgcn_exp2f(St[kt][qq][3]);
            if (!full) {
              int kg = k0 + kt * 16 + quad * 4;
              int qg = qmin[p] + qq * 16 + l16;
              if (kg + 0 > qg) e0 = 0.f;
              if (kg + 1 > qg) e1 = 0.f;
              if (kg + 2 > qg) e2 = 0.f;
              if (kg + 3 > qg) e3 = 0.f;
            }
            lsum[p][qq] += (e0 + e1) + (e2 + e3);
            short4_t ap;
            ap[0] = __builtin_bit_cast(short, (__bf16)e0);
            ap[1] = __builtin_bit_cast(short, (__bf16)e1);
            ap[2] = __builtin_bit_cast(short, (__bf16)e2);
            ap[3] = __builtin_bit_cast(short, (__bf16)e3);
            // PV straight from registers: O[q][d] tiles over d
#pragma unroll
            for (int cd = 0; cd < 4; ++cd)
              acc[p][qq][cd] = __builtin_amdgcn_mfma_f32_16x16x16bf16_1k(
                  ap, vf[kt][cd], acc[p][qq][cd], 0, 0, 0);
          }
      }
    }
  }

  const int bb = bh >> 4, hh = bh & 15;
#pragma unroll
  for (int p = 0; p < 2; ++p) {
#pragma unroll
    for (int qq = 0; qq < 2; ++qq) {
      float s = lsum[p][qq];
      s += __shfl_xor(s, 16);
      s += __shfl_xor(s, 32);   // all lanes: total for q-col = own l16
      float rinv[4];
#pragma unroll
      for (int i = 0; i < 4; ++i)
        rinv[i] = 1.0f / __shfl(s, (lane & 48) + quad * 4 + i);
#pragma unroll
      for (int c = 0; c < 4; ++c)
#pragma unroll
        for (int i = 0; i < 4; ++i) {
          int q = qmin[p] + qq * 16 + quad * 4 + i;
          float o = acc[p][qq][c][i] * rinv[i];
          ctx[((size_t)(bb * SEQ + q)) * D_MODEL + hh * HD + c * 16 + l16] = (__bf16)o;
        }
    }
  }
}

extern "C" void kernel_launch(void* const* d_in, const int* in_sizes, int n_in,
                              void* d_out, int out_size, void* d_ws, size_t ws_size,
                              hipStream_t stream) {
  const float* x  = (const float*)d_in[0];
  const float* Wq = (const float*)d_in[1];
  const float* Wk = (const float*)d_in[2];
  const float* Wv = (const float*)d_in[3];
  const float* Wo = (const float*)d_in[4];
  const float* bo = (const float*)d_in[5];
  float* out = (float*)d_out;
  char* ws = (char*)d_ws;
  const size_t MB = 1024 * 1024;
  __bf16* xb   = (__bf16*)(ws);             // 16 MB; reused as ctx after attn
  __bf16* Wqkv = (__bf16*)(ws + 16 * MB);   // 6 MB: Wqt|Wkt|Wvt contiguous
  __bf16* Wot  = (__bf16*)(ws + 22 * MB);   // 2 MB
  __bf16* Qh   = (__bf16*)(ws + 24 * MB);   // 16 MB [b,h,n,d], pre-scaled
  __bf16* Kh   = (__bf16*)(ws + 40 * MB);   // 16 MB [b,h,n,d]
  __bf16* Vth  = (__bf16*)(ws + 56 * MB);   // 16 MB [b,h,d,n]
  __bf16* ctx  = xb;                        // alias: xb dead after QKV GEMM

  cvt_x<<<MROWS * D_MODEL / (256 * 4), 256, 0, stream>>>(x, xb);
  cvt_wt4<<<dim3(32, 32, 4), dim3(32, 8), 0, stream>>>(Wq, Wk, Wv, Wo, Wqkv, Wot);

  // QK projection (swapped-operand epilogue), then V projection (natural)
  gemm_bt<0><<<dim3(16, 64), 256, 0, stream>>>(xb, Wqkv, nullptr, Qh);
  gemm_bt<1><<<dim3(8, 64), 256, 0, stream>>>(xb, Wqkv + 2 * 1024 * 1024, nullptr, Vth);

  attn<<<dim3(64, 8), 256, 0, stream>>>(Qh, Kh, Vth, ctx);

  gemm_bt<2><<<dim3(8, 64), 256, 0, stream>>>(ctx, Wot, bo, out);
}